// Round 23
// baseline (176.706 us; speedup 1.0000x reference)
//
#include <hip/hip_runtime.h>

typedef unsigned short u16;
typedef unsigned int   u32;
typedef __attribute__((ext_vector_type(4))) int   i32x4;
typedef __attribute__((ext_vector_type(4))) float f32x4;
typedef __attribute__((ext_vector_type(4))) unsigned short u16x4;
typedef __attribute__((ext_vector_type(8))) unsigned short u16x8;

#define DEVI static __device__ __forceinline__

DEVI u16 f2b(float f) {
  u32 u = __builtin_bit_cast(u32, f);
  return (u16)((u + 0x7FFFu + ((u >> 16) & 1u)) >> 16);   // RNE
}

DEVI float b2f(u16 v) {
  u32 u = (u32)v << 16;
  return __builtin_bit_cast(float, u);
}

DEVI float exp2_hw(float x) {          // D = 2^S0 (v_exp_f32)
  float r;
  asm("v_exp_f32 %0, %1" : "=v"(r) : "v"(x));
  return r;
}

DEVI void mfma16(f32x4& d, i32x4 a, i32x4 b) {
  asm("v_mfma_f32_16x16x32_bf16 %0, %1, %2, %0" : "+v"(d) : "v"(a), "v"(b));
}

DEVI void gload16(const void* g, void* l) {
  __builtin_amdgcn_global_load_lds(
      (const __attribute__((address_space(1))) void*)g,
      (__attribute__((address_space(3))) void*)l, 16, 0, 0);
}

// XOR swizzle for 128B-row LDS tiles (8 16B slots/row): slot ^= row&7
DEVI int swz(int row, int b) {
  return (row << 7) + (((b >> 4) ^ (row & 7)) << 4) + (b & 15);
}

// ---------------- merged prep + LN1 bodies ----------------
DEVI void trans_body(const float* __restrict__ src, u16* __restrict__ dst,
                     int R, int C, int rb, int cb, int t, u16 (*tile)[72])
{
  const int tr = t >> 2, tc = (t & 3) * 16;
  const float* sp = src + (size_t)(rb + tr) * C + cb + tc;
  #pragma unroll
  for (int q = 0; q < 4; q++) {
    float4 v = *(const float4*)(sp + q * 4);
    tile[tr][tc + q*4 + 0] = f2b(v.x);
    tile[tr][tc + q*4 + 1] = f2b(v.y);
    tile[tr][tc + q*4 + 2] = f2b(v.z);
    tile[tr][tc + q*4 + 3] = f2b(v.w);
  }
  __syncthreads();
  const int dc = t >> 2, dr = (t & 3) * 16;
  u16x8 o0, o1;
  #pragma unroll
  for (int j = 0; j < 8; j++) { o0[j] = tile[dr + j][dc]; o1[j] = tile[dr + 8 + j][dc]; }
  u16* dp = dst + (size_t)(cb + dc) * R + rb + dr;
  *(u16x8*)(dp) = o0;
  *(u16x8*)(dp + 8) = o1;
}

DEVI void ln_body(const float* __restrict__ x, const float* __restrict__ gamma,
                  const float* __restrict__ beta, u16* __restrict__ out,
                  int blk, int tid)
{
  const int lane = tid & 63;
  const int row = blk * 4 + (tid >> 6);
  const float4* xr = (const float4*)(x + (size_t)row * 512) + lane * 2;
  float4 a0 = xr[0], a1 = xr[1];
  float s  = a0.x + a0.y + a0.z + a0.w + a1.x + a1.y + a1.z + a1.w;
  float sq = a0.x*a0.x + a0.y*a0.y + a0.z*a0.z + a0.w*a0.w
           + a1.x*a1.x + a1.y*a1.y + a1.z*a1.z + a1.w*a1.w;
  #pragma unroll
  for (int o = 32; o > 0; o >>= 1) { s += __shfl_xor(s, o); sq += __shfl_xor(sq, o); }
  const float mu = s * (1.0f / 512.0f);
  const float rstd = rsqrtf(sq * (1.0f / 512.0f) - mu * mu + 1e-5f);
  const float4* g4 = (const float4*)gamma + lane * 2;
  const float4* b4 = (const float4*)beta  + lane * 2;
  float4 g0 = g4[0], g1 = g4[1], b0 = b4[0], b1 = b4[1];
  float xv[8] = {a0.x,a0.y,a0.z,a0.w,a1.x,a1.y,a1.z,a1.w};
  float gv[8] = {g0.x,g0.y,g0.z,g0.w,g1.x,g1.y,g1.z,g1.w};
  float bv[8] = {b0.x,b0.y,b0.z,b0.w,b1.x,b1.y,b1.z,b1.w};
  u16x8 ov;
  #pragma unroll
  for (int j = 0; j < 8; j++) ov[j] = f2b((xv[j] - mu) * rstd * gv[j] + bv[j]);
  *(u16x8*)(out + (size_t)row * 512 + lane * 8) = ov;
}

// grid 2816 = 2048 LN1 | 192 QKV-pack | 64 Wp | 256 W1 | 256 W2
__global__ __launch_bounds__(256) void prep_ln(
    const float* __restrict__ x, const float* __restrict__ ln1g,
    const float* __restrict__ ln1b, u16* __restrict__ hbuf,
    const float* __restrict__ Wq, const float* __restrict__ Wk,
    const float* __restrict__ Wv, u16* __restrict__ Wqkv,
    const float* __restrict__ Wp, u16* __restrict__ Wpt,
    const float* __restrict__ W1, u16* __restrict__ W1t,
    const float* __restrict__ W2, u16* __restrict__ W2t)
{
  __shared__ u16 tile[64][72];
  const int t = threadIdx.x;
  int b = blockIdx.x;
  if (b < 2048) { ln_body(x, ln1g, ln1b, hbuf, b, t); return; }
  b -= 2048;
  if (b < 192) {   // QKV pack: W_widx[h] (512x64) ^T -> Wqkv rows widx*512+h*64
    const int widx = b >> 6, h = (b >> 3) & 7, rb = (b & 7) * 64;
    const float* W = (widx == 0) ? Wq : (widx == 1) ? Wk : Wv;
    trans_body(W + (size_t)h * 512 * 64, Wqkv + (size_t)(widx * 512 + h * 64) * 512,
               512, 64, rb, 0, t, tile);
    return;
  }
  b -= 192;
  if (b < 64)  { trans_body(Wp, Wpt, 512, 512,  (b & 7) * 64, (b >> 3) * 64, t, tile); return; }
  b -= 64;
  if (b < 256) { trans_body(W1, W1t, 512, 2048, (b & 7) * 64, (b >> 3) * 64, t, tile); return; }
  b -= 256;
  trans_body(W2, W2t, 2048, 512, (b & 31) * 64, (b >> 5) * 64, t, tile);
}

// ---------------- LayerNorm over bf16 input (LN2 on x1b) ----------------
__global__ __launch_bounds__(256) void ln_kernel_b(
    const u16* __restrict__ x, const float* __restrict__ gamma,
    const float* __restrict__ beta, u16* __restrict__ out)
{
  const int tid = threadIdx.x;
  const int lane = tid & 63;
  const int row = blockIdx.x * 4 + (tid >> 6);
  u16x8 xr = *(const u16x8*)(x + (size_t)row * 512 + lane * 8);
  float xv[8];
  #pragma unroll
  for (int j = 0; j < 8; j++) xv[j] = b2f(xr[j]);
  float s = 0.0f, sq = 0.0f;
  #pragma unroll
  for (int j = 0; j < 8; j++) { s += xv[j]; sq += xv[j] * xv[j]; }
  #pragma unroll
  for (int o = 32; o > 0; o >>= 1) { s += __shfl_xor(s, o); sq += __shfl_xor(sq, o); }
  const float mu = s * (1.0f / 512.0f);
  const float rstd = rsqrtf(sq * (1.0f / 512.0f) - mu * mu + 1e-5f);
  const float4* g4 = (const float4*)gamma + lane * 2;
  const float4* b4 = (const float4*)beta  + lane * 2;
  float4 g0 = g4[0], g1 = g4[1], b0 = b4[0], b1 = b4[1];
  float gv[8] = {g0.x,g0.y,g0.z,g0.w,g1.x,g1.y,g1.z,g1.w};
  float bv[8] = {b0.x,b0.y,b0.z,b0.w,b1.x,b1.y,b1.z,b1.w};
  u16x8 ov;
  #pragma unroll
  for (int j = 0; j < 8; j++) ov[j] = f2b((xv[j] - mu) * rstd * gv[j] + bv[j]);
  *(u16x8*)(out + (size_t)row * 512 + lane * 8) = ov;
}

// ---------------- GEMM: MTx128 tile, 3-deep pipelined staging ----------------
// (round-14 verified orientation; do NOT swap mfma operands — R15 refcheck fail)
// MT=128 for >=3 blocks/CU (QKV, FFN1); MT=64 only for 1-block/CU cases (proj,
// FFN2) — R20: MT=64 on QKV/FFN1 costs ~10us.
// EPI 0: QKV scatter | EPI 2: +bias,relu->bf16 | EPI 3: +bias+fp32resid->bf16
// EPI 4: +bias+bf16resid->fp32
template<int KD, int MT, int EPI>
__global__ __launch_bounds__(256) void gemm_bt(
    const u16* __restrict__ A, const u16* __restrict__ Bt,
    const float* __restrict__ bias0, const float* __restrict__ bias1,
    const float* __restrict__ bias2, const float* __restrict__ resid,
    void* __restrict__ out0, void* __restrict__ out1, void* __restrict__ out2)
{
  __shared__ __align__(16) u16 sA[3][MT * 32];
  __shared__ __align__(16) u16 sB[3][128 * 32];
  constexpr int NSTEP = KD / 32;
  constexpr int MTILES = 8192 / MT;
  constexpr int WC = (MT == 128) ? 2 : 4;
  constexpr int MI = 4;
  constexpr int NJ = 8 / WC;
  constexpr int LA = MT / 64;
  const int tid = threadIdx.x, lane = tid & 63, w = tid >> 6;
  const int m0 = (blockIdx.x % MTILES) * MT, n0 = (blockIdx.x / MTILES) * 128;
  const int wr = w / WC, wc = w % WC, r = lane & 15, gq = lane >> 4;

  f32x4 acc[MI][NJ] = {};

  const char* Ab = (const char*)A;
  const char* Bb = (const char*)Bt;

#define STAGE(step, buf) do {                                                  \
    const int kbyte_ = (step) * 64;                                            \
    _Pragma("unroll")                                                          \
    for (int la_ = 0; la_ < LA; la_++) {                                       \
      int o_ = la_ * 4096 + tid * 16;                                          \
      gload16(Ab + (size_t)(m0 + (o_ >> 6)) * (KD * 2) + kbyte_ + (o_ & 63),   \
              (char*)sA + (buf) * (MT * 64) + o_);                             \
    }                                                                          \
    _Pragma("unroll")                                                          \
    for (int lb_ = 0; lb_ < 2; lb_++) {                                        \
      int o_ = lb_ * 4096 + tid * 16;                                          \
      gload16(Bb + (size_t)(n0 + (o_ >> 6)) * (KD * 2) + kbyte_ + (o_ & 63),   \
              (char*)sB + (buf) * 8192 + o_);                                  \
    }                                                                          \
  } while (0)

  STAGE(0, 0);
  STAGE(1, 1);

  for (int t = 0; t < NSTEP; t++) {
    __builtin_amdgcn_sched_barrier(0);
    __builtin_amdgcn_s_barrier();
    if (t + 2 < NSTEP) {
      STAGE(t + 2, (t + 2) % 3);
      if constexpr (MT == 128) asm volatile("s_waitcnt vmcnt(8)" ::: "memory");
      else                     asm volatile("s_waitcnt vmcnt(6)" ::: "memory");
    } else if (t + 1 < NSTEP) {
      if constexpr (MT == 128) asm volatile("s_waitcnt vmcnt(4)" ::: "memory");
      else                     asm volatile("s_waitcnt vmcnt(3)" ::: "memory");
    } else {
      asm volatile("s_waitcnt vmcnt(0)" ::: "memory");
    }
    __builtin_amdgcn_sched_barrier(0);
    __builtin_amdgcn_s_barrier();
    const u16* sAc = sA[t % 3];
    const u16* sBc = sB[t % 3];
    i32x4 af[MI], bfr[NJ];
    #pragma unroll
    for (int i = 0; i < MI; i++)
      af[i] = *(const i32x4*)(sAc + (wr * (MI * 16) + i * 16 + r) * 32 + gq * 8);
    #pragma unroll
    for (int j = 0; j < NJ; j++)
      bfr[j] = *(const i32x4*)(sBc + (wc * (NJ * 16) + j * 16 + r) * 32 + gq * 8);
    #pragma unroll
    for (int i = 0; i < MI; i++)
      #pragma unroll
      for (int j = 0; j < NJ; j++)
        mfma16(acc[i][j], af[i], bfr[j]);
  }
#undef STAGE

  #pragma unroll
  for (int i = 0; i < MI; i++) {
    #pragma unroll
    for (int j = 0; j < NJ; j++) {
      const int mb = m0 + wr * (MI * 16) + i * 16 + gq * 4;
      const int nc = n0 + wc * (NJ * 16) + j * 16 + r;
      #pragma unroll
      for (int e = 0; e < 4; e++) {
        const int m = mb + e;
        float v = acc[i][j][e];
        if (EPI == 0) {
          float bias; u16* dst;
          if (nc < 512)       { bias = bias0[nc];        dst = (u16*)out0; }
          else if (nc < 1024) { bias = bias1[nc - 512];  dst = (u16*)out1; }
          else                { bias = bias2[nc - 1024]; dst = (u16*)out2; }
          v += bias;
          const int nn = nc & 511, h = nn >> 6, d = nn & 63;
          const int bb = m >> 11, tt = m & 2047;
          dst[(size_t)((bb * 8 + h) * 2048 + tt) * 64 + d] = f2b(v);
        } else if (EPI == 2) {
          v += bias0[nc];
          v = fmaxf(v, 0.0f);
          ((u16*)out0)[(size_t)m * 2048 + nc] = f2b(v);
        } else if (EPI == 3) {
          v += bias0[nc] + resid[(size_t)m * 512 + nc];
          ((u16*)out0)[(size_t)m * 512 + nc] = f2b(v);
        } else {   // EPI == 4
          const u16* rb_ = (const u16*)resid;
          v += bias0[nc] + b2f(rb_[(size_t)m * 512 + nc]);
          ((float*)out0)[(size_t)m * 512 + nc] = v;
        }
      }
    }
  }
}

// ---------------- causal flash attention v7: TWO q-tiles per block ----------------
// grid 512 = 16 pslots x 32 bh (bh fastest). qt0 = p<8 ? p : 23-p (in [0,16)),
// qt1 = qt0+16; co-resident pairs {p,p+8} sum to 49 iterations -> balanced CUs.
// Both q-tiles share K/V staging; independent softmax chains interleave (ILP).
__global__ __launch_bounds__(256) void attn_kernel(
    const u16* __restrict__ Q, const u16* __restrict__ K,
    const u16* __restrict__ V, u16* __restrict__ O)
{
  __shared__ __align__(16) char lds[32768];  // K dbuf 0..16K | Vt dbuf 16K..32K
  const int tid = threadIdx.x, lane = tid & 63, w = tid >> 6;
  const int bh = blockIdx.x & 31, p = blockIdx.x >> 5;
  const int qt0 = (p < 8) ? p : (23 - p);
  const int qt1 = qt0 + 16;
  const int r = lane & 15, gq = lane >> 4;
  const u16* Qb = Q + (size_t)bh * (2048 * 64);
  const u16* Kb = K + (size_t)bh * (2048 * 64);
  const u16* Vb = V + (size_t)bh * (2048 * 64);
  const int bb = bh >> 3, hh = bh & 7;

  const int sv = (tid & 15) * 4;   // V-stage: local s base
  const int dv = (tid >> 4) * 4;   // V-stage: d base
  u16x4 vr[4];
  const float SC2 = 0.125f * 1.44269504f;   // log2 domain

#define STAGEK(s0g, buf) do {                                              \
    _Pragma("unroll")                                                      \
    for (int i_ = 0; i_ < 2; i_++) {                                       \
      int o_ = w * 2048 + i_ * 1024 + lane * 16;                           \
      int so_ = o_ ^ (((o_ >> 7) & 7) << 4);                               \
      gload16((const char*)(Kb + (size_t)(s0g) * 64) + so_,                \
              lds + (buf) * 8192 + w * 2048 + i_ * 1024);                  \
    } } while (0)

#define LOADV(s0g) do {                                                    \
    _Pragma("unroll")                                                      \
    for (int j_ = 0; j_ < 4; j_++)                                         \
      vr[j_] = *(const u16x4*)(Vb + (size_t)((s0g) + sv + j_) * 64 + dv);  \
    } while (0)

#define WRITEV(buf) do {                                                   \
    _Pragma("unroll")                                                      \
    for (int dd_ = 0; dd_ < 4; dd_++) {                                    \
      u16x4 val_ = {vr[0][dd_], vr[1][dd_], vr[2][dd_], vr[3][dd_]};       \
      *(u16x4*)(lds + 16384 + (buf) * 8192 + swz(dv + dd_, sv * 2)) = val_;\
    } } while (0)

// per-q-tile step: QK^T -> online softmax -> PV (state passed by name)
#define QSTEP(qf, accO, m_run, l_run, qg, isdiag) do {                        \
    f32x4 st[4] = {};                                                          \
    const int sbmax_ = (isdiag) ? (w + 1) : 4;                                 \
    _Pragma("unroll")                                                          \
    for (int kd = 0; kd < 2; kd++)                                             \
      _Pragma("unroll")                                                        \
      for (int sb = 0; sb < 4; sb++)                                           \
        if (sb < sbmax_) {                                                     \
          i32x4 kf = *(const i32x4*)(lds + cb * 8192 + swz(sb * 16 + r, kd * 64 + gq * 16)); \
          mfma16(st[sb], kf, qf[kd]);                                          \
        }                                                                      \
    float tmax = -1e30f;                                                       \
    if (isdiag) {                                                              \
      _Pragma("unroll")                                                        \
      for (int sb = 0; sb < 4; sb++)                                           \
        _Pragma("unroll")                                                      \
        for (int e = 0; e < 4; e++) {                                          \
          int sg = s0 + sb * 16 + gq * 4 + e;                                  \
          float v = st[sb][e] * SC2;                                           \
          v = (sg <= (qg)) ? v : -1e30f;                                       \
          st[sb][e] = v;                                                       \
          tmax = fmaxf(tmax, v);                                               \
        }                                                                      \
    } else {                                                                   \
      _Pragma("unroll")                                                        \
      for (int sb = 0; sb < 4; sb++)                                           \
        _Pragma("unroll")                                                      \
        for (int e = 0; e < 4; e++) {                                          \
          float v = st[sb][e] * SC2;                                           \
          st[sb][e] = v;                                                       \
          tmax = fmaxf(tmax, v);                                               \
        }                                                                      \
    }                                                                          \
    tmax = fmaxf(tmax, __shfl_xor(tmax, 16));                                  \
    tmax = fmaxf(tmax, __shfl_xor(tmax, 32));                                  \
    if (!__all(tmax <= m_run)) {                                               \
      const float mnew = fmaxf(m_run, tmax);                                   \
      const float alpha = exp2_hw(m_run - mnew);                               \
      l_run *= alpha;                                                          \
      _Pragma("unroll")                                                        \
      for (int db = 0; db < 4; db++)                                           \
        _Pragma("unroll")                                                      \
        for (int e = 0; e < 4; e++) accO[db][e] *= alpha;                      \
      m_run = mnew;                                                            \
    }                                                                          \
    float rsum = 0.0f;                                                         \
    _Pragma("unroll")                                                          \
    for (int sb = 0; sb < 4; sb++)                                             \
      _Pragma("unroll")                                                        \
      for (int e = 0; e < 4; e++) {                                            \
        float pv = exp2_hw(st[sb][e] - m_run);                                 \
        st[sb][e] = pv;                                                        \
        rsum += pv;                                                            \
      }                                                                        \
    rsum += __shfl_xor(rsum, 16);                                              \
    rsum += __shfl_xor(rsum, 32);                                              \
    l_run += rsum;                                                             \
    const int kmax_ = (isdiag) ? ((w >> 1) + 1) : 2;                           \
    _Pragma("unroll")                                                          \
    for (int ks = 0; ks < 2; ks++)                                             \
      if (ks < kmax_) {                                                        \
        u32 w0_, w1_, w2_, w3_;                                                \
        asm("v_cvt_pk_bf16_f32 %0, %1, %2" : "=v"(w0_) : "v"(st[2*ks][0]),   "v"(st[2*ks][1]));   \
        asm("v_cvt_pk_bf16_f32 %0, %1, %2" : "=v"(w1_) : "v"(st[2*ks][2]),   "v"(st[2*ks][3]));   \
        asm("v_cvt_pk_bf16_f32 %0, %1, %2" : "=v"(w2_) : "v"(st[2*ks+1][0]), "v"(st[2*ks+1][1])); \
        asm("v_cvt_pk_bf16_f32 %0, %1, %2" : "=v"(w3_) : "v"(st[2*ks+1][2]), "v"(st[2*ks+1][3])); \
        i32x4 pf = {(int)w0_, (int)w1_, (int)w2_, (int)w3_};                   \
        _Pragma("unroll")                                                      \
        for (int db = 0; db < 4; db++) {                                       \
          uint2 a0 = *(const uint2*)(lds + 16384 + cb * 8192 + swz(db * 16 + r, ks * 64 + gq * 8));      \
          uint2 a1 = *(const uint2*)(lds + 16384 + cb * 8192 + swz(db * 16 + r, ks * 64 + gq * 8 + 32)); \
          i32x4 vfr = {(int)a0.x, (int)a0.y, (int)a1.x, (int)a1.y};            \
          mfma16(accO[db], vfr, pf);                                           \
        }                                                                      \
      }                                                                        \
  } while (0)

  const int q0_0 = qt0 << 6, q0_1 = qt1 << 6;
  const int qg0 = q0_0 + w * 16 + r, qg1 = q0_1 + w * 16 + r;

  i32x4 qf0[2], qf1[2];
  qf0[0] = *(const i32x4*)(Qb + (size_t)(q0_0 + w * 16 + r) * 64 + gq * 8);
  qf0[1] = *(const i32x4*)(Qb + (size_t)(q0_0 + w * 16 + r) * 64 + 32 + gq * 8);
  qf1[0] = *(const i32x4*)(Qb + (size_t)(q0_1 + w * 16 + r) * 64 + gq * 8);
  qf1[1] = *(const i32x4*)(Qb + (size_t)(q0_1 + w * 16 + r) * 64 + 32 + gq * 8);

  STAGEK(0, 0);
  LOADV(0);
  WRITEV(0);
  __syncthreads();

  f32x4 accO0[4] = {}, accO1[4] = {};
  float m0r = -1e30f, l0r = 0.0f, m1r = -1e30f, l1r = 0.0f;

  for (int t = 0; t <= qt1; t++) {
    const int cb = t & 1, nb = cb ^ 1;
    const int s0 = t << 6;
    if (t < qt1) {           // issue next-tile loads BEFORE compute
      STAGEK(s0 + 64, nb);
      LOADV(s0 + 64);
    }

    QSTEP(qf1, accO1, m1r, l1r, qg1, (t == qt1));
    if (t <= qt0) {
      QSTEP(qf0, accO0, m0r, l0r, qg0, (t == qt0));
    }

    if (t < qt1) WRITEV(nb);
    __syncthreads();
  }

  // epilogues: accO[db][e] = O[q=q0+w*16+r][d=db*16+gq*4+e], scale 1/l
  {
    const float li = 1.0f / l0r;
    const int qrow = q0_0 + w * 16 + r;
    #pragma unroll
    for (int db = 0; db < 4; db++) {
      u16x4 ov;
      #pragma unroll
      for (int e = 0; e < 4; e++) ov[e] = f2b(accO0[db][e] * li);
      *(u16x4*)(O + (size_t)(bb * 2048 + qrow) * 512 + hh * 64 + db * 16 + gq * 4) = ov;
    }
  }
  {
    const float li = 1.0f / l1r;
    const int qrow = q0_1 + w * 16 + r;
    #pragma unroll
    for (int db = 0; db < 4; db++) {
      u16x4 ov;
      #pragma unroll
      for (int e = 0; e < 4; e++) ov[e] = f2b(accO1[db][e] * li);
      *(u16x4*)(O + (size_t)(bb * 2048 + qrow) * 512 + hh * 64 + db * 16 + gq * 4) = ov;
    }
  }
#undef QSTEP
#undef STAGEK
#undef LOADV
#undef WRITEV
}

// ---------------- launcher ----------------
extern "C" void kernel_launch(void* const* d_in, const int* in_sizes, int n_in,
                              void* d_out, int out_size, void* d_ws, size_t ws_size,
                              hipStream_t stream)
{
  const float* x    = (const float*)d_in[0];
  const float* ln1g = (const float*)d_in[1];
  const float* ln1b = (const float*)d_in[2];
  const float* Wq   = (const float*)d_in[3];
  const float* bq   = (const float*)d_in[4];
  const float* Wk   = (const float*)d_in[5];
  const float* bk   = (const float*)d_in[6];
  const float* Wv   = (const float*)d_in[7];
  const float* bv   = (const float*)d_in[8];
  const float* Wp   = (const float*)d_in[9];
  const float* bp   = (const float*)d_in[10];
  const float* ln2g = (const float*)d_in[11];
  const float* ln2b = (const float*)d_in[12];
  const float* W1   = (const float*)d_in[13];
  const float* b1   = (const float*)d_in[14];
  const float* W2   = (const float*)d_in[15];
  const float* b2   = (const float*)d_in[16];

  char* ws = (char*)d_ws;
  const size_t MB = 1ull << 20;
  u16* x1b   = (u16*)(ws);                // 8 MB bf16 [8192,512] (x + attn)
  u16* hbuf  = (u16*)(ws + 16 * MB);      // 8 MB
  u16* Qb    = (u16*)(ws + 24 * MB);      // 8 MB  [B,H,T,64]
  u16* Kb    = (u16*)(ws + 32 * MB);      // 8 MB
  u16* Vb    = (u16*)(ws + 40 * MB);      // 8 MB
  u16* attn  = (u16*)(ws + 48 * MB);      // 8 MB  [8192,512]
  u16* fbuf  = (u16*)(ws + 24 * MB);      // 32 MB [8192,2048] (reuses dead QKV+attn)
  u16* Wqkv  = (u16*)(ws + 56 * MB);      // 1.5 MB [1536,512]
  u16* Wpt   = (u16*)(ws + 58 * MB);      // 0.5 MB [512,512]
  u16* W1t   = (u16*)(ws + 59 * MB);      // 2 MB  [2048,512]
  u16* W2t   = (u16*)(ws + 61 * MB);      // 2 MB  [512,2048]
  float* outf = (float*)d_out;

  prep_ln<<<2816, 256, 0, stream>>>(x, ln1g, ln1b, hbuf,
                                    Wq, Wk, Wv, Wqkv,
                                    Wp, Wpt, W1, W1t, W2, W2t);
  gemm_bt<512, 128, 0><<<768, 256, 0, stream>>>(hbuf, Wqkv, bq, bk, bv,
                                                nullptr, Qb, Kb, Vb);
  attn_kernel<<<512, 256, 0, stream>>>(Qb, Kb, Vb, attn);
  gemm_bt<512, 64, 3><<<512, 256, 0, stream>>>(attn, Wpt, bp, nullptr, nullptr,
                                               x, x1b, nullptr, nullptr);
  ln_kernel_b<<<2048, 256, 0, stream>>>(x1b, ln2g, ln2b, hbuf);
  gemm_bt<512, 128, 2><<<1024, 256, 0, stream>>>(hbuf, W1t, b1, nullptr, nullptr,
                                                 nullptr, fbuf, nullptr, nullptr);
  gemm_bt<2048, 64, 4><<<512, 256, 0, stream>>>(fbuf, W2t, b2, nullptr, nullptr,
                                                (const float*)x1b, outf, nullptr, nullptr);
}

// Round 24
// 159.537 us; speedup vs baseline: 1.1076x; 1.1076x over previous
//
#include <hip/hip_runtime.h>

typedef unsigned short u16;
typedef unsigned int   u32;
typedef __attribute__((ext_vector_type(4))) int   i32x4;
typedef __attribute__((ext_vector_type(4))) float f32x4;
typedef __attribute__((ext_vector_type(4))) unsigned short u16x4;
typedef __attribute__((ext_vector_type(8))) unsigned short u16x8;

#define DEVI static __device__ __forceinline__

DEVI u16 f2b(float f) {
  u32 u = __builtin_bit_cast(u32, f);
  return (u16)((u + 0x7FFFu + ((u >> 16) & 1u)) >> 16);   // RNE
}

DEVI float b2f(u16 v) {
  u32 u = (u32)v << 16;
  return __builtin_bit_cast(float, u);
}

DEVI float exp2_hw(float x) {          // D = 2^S0 (v_exp_f32)
  float r;
  asm("v_exp_f32 %0, %1" : "=v"(r) : "v"(x));
  return r;
}

DEVI void mfma16(f32x4& d, i32x4 a, i32x4 b) {
  asm("v_mfma_f32_16x16x32_bf16 %0, %1, %2, %0" : "+v"(d) : "v"(a), "v"(b));
}

DEVI void gload16(const void* g, void* l) {
  __builtin_amdgcn_global_load_lds(
      (const __attribute__((address_space(1))) void*)g,
      (__attribute__((address_space(3))) void*)l, 16, 0, 0);
}

// XOR swizzle for 128B-row LDS tiles (8 16B slots/row): slot ^= row&7
DEVI int swz(int row, int b) {
  return (row << 7) + (((b >> 4) ^ (row & 7)) << 4) + (b & 15);
}

// ---------------- merged prep + LN1 bodies ----------------
DEVI void trans_body(const float* __restrict__ src, u16* __restrict__ dst,
                     int R, int C, int rb, int cb, int t, u16 (*tile)[72])
{
  const int tr = t >> 2, tc = (t & 3) * 16;
  const float* sp = src + (size_t)(rb + tr) * C + cb + tc;
  #pragma unroll
  for (int q = 0; q < 4; q++) {
    float4 v = *(const float4*)(sp + q * 4);
    tile[tr][tc + q*4 + 0] = f2b(v.x);
    tile[tr][tc + q*4 + 1] = f2b(v.y);
    tile[tr][tc + q*4 + 2] = f2b(v.z);
    tile[tr][tc + q*4 + 3] = f2b(v.w);
  }
  __syncthreads();
  const int dc = t >> 2, dr = (t & 3) * 16;
  u16x8 o0, o1;
  #pragma unroll
  for (int j = 0; j < 8; j++) { o0[j] = tile[dr + j][dc]; o1[j] = tile[dr + 8 + j][dc]; }
  u16* dp = dst + (size_t)(cb + dc) * R + rb + dr;
  *(u16x8*)(dp) = o0;
  *(u16x8*)(dp + 8) = o1;
}

DEVI void ln_body(const float* __restrict__ x, const float* __restrict__ gamma,
                  const float* __restrict__ beta, u16* __restrict__ out,
                  int blk, int tid)
{
  const int lane = tid & 63;
  const int row = blk * 4 + (tid >> 6);
  const float4* xr = (const float4*)(x + (size_t)row * 512) + lane * 2;
  float4 a0 = xr[0], a1 = xr[1];
  float s  = a0.x + a0.y + a0.z + a0.w + a1.x + a1.y + a1.z + a1.w;
  float sq = a0.x*a0.x + a0.y*a0.y + a0.z*a0.z + a0.w*a0.w
           + a1.x*a1.x + a1.y*a1.y + a1.z*a1.z + a1.w*a1.w;
  #pragma unroll
  for (int o = 32; o > 0; o >>= 1) { s += __shfl_xor(s, o); sq += __shfl_xor(sq, o); }
  const float mu = s * (1.0f / 512.0f);
  const float rstd = rsqrtf(sq * (1.0f / 512.0f) - mu * mu + 1e-5f);
  const float4* g4 = (const float4*)gamma + lane * 2;
  const float4* b4 = (const float4*)beta  + lane * 2;
  float4 g0 = g4[0], g1 = g4[1], b0 = b4[0], b1 = b4[1];
  float xv[8] = {a0.x,a0.y,a0.z,a0.w,a1.x,a1.y,a1.z,a1.w};
  float gv[8] = {g0.x,g0.y,g0.z,g0.w,g1.x,g1.y,g1.z,g1.w};
  float bv[8] = {b0.x,b0.y,b0.z,b0.w,b1.x,b1.y,b1.z,b1.w};
  u16x8 ov;
  #pragma unroll
  for (int j = 0; j < 8; j++) ov[j] = f2b((xv[j] - mu) * rstd * gv[j] + bv[j]);
  *(u16x8*)(out + (size_t)row * 512 + lane * 8) = ov;
}

// grid 2816 = 2048 LN1 | 192 QKV-pack | 64 Wp | 256 W1 | 256 W2
__global__ __launch_bounds__(256) void prep_ln(
    const float* __restrict__ x, const float* __restrict__ ln1g,
    const float* __restrict__ ln1b, u16* __restrict__ hbuf,
    const float* __restrict__ Wq, const float* __restrict__ Wk,
    const float* __restrict__ Wv, u16* __restrict__ Wqkv,
    const float* __restrict__ Wp, u16* __restrict__ Wpt,
    const float* __restrict__ W1, u16* __restrict__ W1t,
    const float* __restrict__ W2, u16* __restrict__ W2t)
{
  __shared__ u16 tile[64][72];
  const int t = threadIdx.x;
  int b = blockIdx.x;
  if (b < 2048) { ln_body(x, ln1g, ln1b, hbuf, b, t); return; }
  b -= 2048;
  if (b < 192) {   // QKV pack: W_widx[h] (512x64) ^T -> Wqkv rows widx*512+h*64
    const int widx = b >> 6, h = (b >> 3) & 7, rb = (b & 7) * 64;
    const float* W = (widx == 0) ? Wq : (widx == 1) ? Wk : Wv;
    trans_body(W + (size_t)h * 512 * 64, Wqkv + (size_t)(widx * 512 + h * 64) * 512,
               512, 64, rb, 0, t, tile);
    return;
  }
  b -= 192;
  if (b < 64)  { trans_body(Wp, Wpt, 512, 512,  (b & 7) * 64, (b >> 3) * 64, t, tile); return; }
  b -= 64;
  if (b < 256) { trans_body(W1, W1t, 512, 2048, (b & 7) * 64, (b >> 3) * 64, t, tile); return; }
  b -= 256;
  trans_body(W2, W2t, 2048, 512, (b & 31) * 64, (b >> 5) * 64, t, tile);
}

// ---------------- LayerNorm over bf16 input (LN2 on x1b) ----------------
__global__ __launch_bounds__(256) void ln_kernel_b(
    const u16* __restrict__ x, const float* __restrict__ gamma,
    const float* __restrict__ beta, u16* __restrict__ out)
{
  const int tid = threadIdx.x;
  const int lane = tid & 63;
  const int row = blockIdx.x * 4 + (tid >> 6);
  u16x8 xr = *(const u16x8*)(x + (size_t)row * 512 + lane * 8);
  float xv[8];
  #pragma unroll
  for (int j = 0; j < 8; j++) xv[j] = b2f(xr[j]);
  float s = 0.0f, sq = 0.0f;
  #pragma unroll
  for (int j = 0; j < 8; j++) { s += xv[j]; sq += xv[j] * xv[j]; }
  #pragma unroll
  for (int o = 32; o > 0; o >>= 1) { s += __shfl_xor(s, o); sq += __shfl_xor(sq, o); }
  const float mu = s * (1.0f / 512.0f);
  const float rstd = rsqrtf(sq * (1.0f / 512.0f) - mu * mu + 1e-5f);
  const float4* g4 = (const float4*)gamma + lane * 2;
  const float4* b4 = (const float4*)beta  + lane * 2;
  float4 g0 = g4[0], g1 = g4[1], b0 = b4[0], b1 = b4[1];
  float gv[8] = {g0.x,g0.y,g0.z,g0.w,g1.x,g1.y,g1.z,g1.w};
  float bv[8] = {b0.x,b0.y,b0.z,b0.w,b1.x,b1.y,b1.z,b1.w};
  u16x8 ov;
  #pragma unroll
  for (int j = 0; j < 8; j++) ov[j] = f2b((xv[j] - mu) * rstd * gv[j] + bv[j]);
  *(u16x8*)(out + (size_t)row * 512 + lane * 8) = ov;
}

// ---------------- GEMM: MTx128 tile, 3-deep pipelined staging ----------------
// (round-14 verified orientation; do NOT swap mfma operands — R15 refcheck fail)
// MT=128 for >=3 blocks/CU (QKV, FFN1); MT=64 only for 1-block/CU cases (proj,
// FFN2) — R20: MT=64 on QKV/FFN1 costs ~10us.
// EPI 0: QKV scatter | EPI 2: +bias,relu->bf16 | EPI 3: +bias+fp32resid->bf16
// EPI 4: +bias+bf16resid->fp32
template<int KD, int MT, int EPI>
__global__ __launch_bounds__(256) void gemm_bt(
    const u16* __restrict__ A, const u16* __restrict__ Bt,
    const float* __restrict__ bias0, const float* __restrict__ bias1,
    const float* __restrict__ bias2, const float* __restrict__ resid,
    void* __restrict__ out0, void* __restrict__ out1, void* __restrict__ out2)
{
  __shared__ __align__(16) u16 sA[3][MT * 32];
  __shared__ __align__(16) u16 sB[3][128 * 32];
  constexpr int NSTEP = KD / 32;
  constexpr int MTILES = 8192 / MT;
  constexpr int WC = (MT == 128) ? 2 : 4;
  constexpr int MI = 4;
  constexpr int NJ = 8 / WC;
  constexpr int LA = MT / 64;
  const int tid = threadIdx.x, lane = tid & 63, w = tid >> 6;
  const int m0 = (blockIdx.x % MTILES) * MT, n0 = (blockIdx.x / MTILES) * 128;
  const int wr = w / WC, wc = w % WC, r = lane & 15, gq = lane >> 4;

  f32x4 acc[MI][NJ] = {};

  const char* Ab = (const char*)A;
  const char* Bb = (const char*)Bt;

#define STAGE(step, buf) do {                                                  \
    const int kbyte_ = (step) * 64;                                            \
    _Pragma("unroll")                                                          \
    for (int la_ = 0; la_ < LA; la_++) {                                       \
      int o_ = la_ * 4096 + tid * 16;                                          \
      gload16(Ab + (size_t)(m0 + (o_ >> 6)) * (KD * 2) + kbyte_ + (o_ & 63),   \
              (char*)sA + (buf) * (MT * 64) + o_);                             \
    }                                                                          \
    _Pragma("unroll")                                                          \
    for (int lb_ = 0; lb_ < 2; lb_++) {                                        \
      int o_ = lb_ * 4096 + tid * 16;                                          \
      gload16(Bb + (size_t)(n0 + (o_ >> 6)) * (KD * 2) + kbyte_ + (o_ & 63),   \
              (char*)sB + (buf) * 8192 + o_);                                  \
    }                                                                          \
  } while (0)

  STAGE(0, 0);
  STAGE(1, 1);

  for (int t = 0; t < NSTEP; t++) {
    __builtin_amdgcn_sched_barrier(0);
    __builtin_amdgcn_s_barrier();
    if (t + 2 < NSTEP) {
      STAGE(t + 2, (t + 2) % 3);
      if constexpr (MT == 128) asm volatile("s_waitcnt vmcnt(8)" ::: "memory");
      else                     asm volatile("s_waitcnt vmcnt(6)" ::: "memory");
    } else if (t + 1 < NSTEP) {
      if constexpr (MT == 128) asm volatile("s_waitcnt vmcnt(4)" ::: "memory");
      else                     asm volatile("s_waitcnt vmcnt(3)" ::: "memory");
    } else {
      asm volatile("s_waitcnt vmcnt(0)" ::: "memory");
    }
    __builtin_amdgcn_sched_barrier(0);
    __builtin_amdgcn_s_barrier();
    const u16* sAc = sA[t % 3];
    const u16* sBc = sB[t % 3];
    i32x4 af[MI], bfr[NJ];
    #pragma unroll
    for (int i = 0; i < MI; i++)
      af[i] = *(const i32x4*)(sAc + (wr * (MI * 16) + i * 16 + r) * 32 + gq * 8);
    #pragma unroll
    for (int j = 0; j < NJ; j++)
      bfr[j] = *(const i32x4*)(sBc + (wc * (NJ * 16) + j * 16 + r) * 32 + gq * 8);
    #pragma unroll
    for (int i = 0; i < MI; i++)
      #pragma unroll
      for (int j = 0; j < NJ; j++)
        mfma16(acc[i][j], af[i], bfr[j]);
  }
#undef STAGE

  #pragma unroll
  for (int i = 0; i < MI; i++) {
    #pragma unroll
    for (int j = 0; j < NJ; j++) {
      const int mb = m0 + wr * (MI * 16) + i * 16 + gq * 4;
      const int nc = n0 + wc * (NJ * 16) + j * 16 + r;
      #pragma unroll
      for (int e = 0; e < 4; e++) {
        const int m = mb + e;
        float v = acc[i][j][e];
        if (EPI == 0) {
          float bias; u16* dst;
          if (nc < 512)       { bias = bias0[nc];        dst = (u16*)out0; }
          else if (nc < 1024) { bias = bias1[nc - 512];  dst = (u16*)out1; }
          else                { bias = bias2[nc - 1024]; dst = (u16*)out2; }
          v += bias;
          const int nn = nc & 511, h = nn >> 6, d = nn & 63;
          const int bb = m >> 11, tt = m & 2047;
          dst[(size_t)((bb * 8 + h) * 2048 + tt) * 64 + d] = f2b(v);
        } else if (EPI == 2) {
          v += bias0[nc];
          v = fmaxf(v, 0.0f);
          ((u16*)out0)[(size_t)m * 2048 + nc] = f2b(v);
        } else if (EPI == 3) {
          v += bias0[nc] + resid[(size_t)m * 512 + nc];
          ((u16*)out0)[(size_t)m * 512 + nc] = f2b(v);
        } else {   // EPI == 4
          const u16* rb_ = (const u16*)resid;
          v += bias0[nc] + b2f(rb_[(size_t)m * 512 + nc]);
          ((float*)out0)[(size_t)m * 512 + nc] = v;
        }
      }
    }
  }
}

// ---------------- causal flash attention v6: in-register P, O^T accumulate ---------------
// grid 1024 = 32 qslots x 32 bh (bh fastest); qt = {s,15-s,16+s,31-s} balance map.
__global__ __launch_bounds__(256) void attn_kernel(
    const u16* __restrict__ Q, const u16* __restrict__ K,
    const u16* __restrict__ V, u16* __restrict__ O)
{
  __shared__ __align__(16) char lds[32768];  // K dbuf 0..16K | Vt dbuf 16K..32K
  const int tid = threadIdx.x, lane = tid & 63, w = tid >> 6;
  const int bh = blockIdx.x & 31, i = blockIdx.x >> 5;
  const int s = i & 7, g = i >> 3;
  const int qt = (g == 0) ? s : (g == 1) ? (15 - s) : (g == 2) ? (16 + s) : (31 - s);
  const int r = lane & 15, gq = lane >> 4;
  const u16* Qb = Q + (size_t)bh * (2048 * 64);
  const u16* Kb = K + (size_t)bh * (2048 * 64);
  const u16* Vb = V + (size_t)bh * (2048 * 64);
  const int bb = bh >> 3, hh = bh & 7;

  const int sv = (tid & 15) * 4;   // V-stage: local s base
  const int dv = (tid >> 4) * 4;   // V-stage: d base
  u16x4 vr[4];
  const float SC2 = 0.125f * 1.44269504f;   // log2 domain

#define STAGEK(s0g, buf) do {                                              \
    _Pragma("unroll")                                                      \
    for (int i_ = 0; i_ < 2; i_++) {                                       \
      int o_ = w * 2048 + i_ * 1024 + lane * 16;                           \
      int so_ = o_ ^ (((o_ >> 7) & 7) << 4);                               \
      gload16((const char*)(Kb + (size_t)(s0g) * 64) + so_,                \
              lds + (buf) * 8192 + w * 2048 + i_ * 1024);                  \
    } } while (0)

#define LOADV(s0g) do {                                                    \
    _Pragma("unroll")                                                      \
    for (int j_ = 0; j_ < 4; j_++)                                         \
      vr[j_] = *(const u16x4*)(Vb + (size_t)((s0g) + sv + j_) * 64 + dv);  \
    } while (0)

#define WRITEV(buf) do {                                                   \
    _Pragma("unroll")                                                      \
    for (int dd_ = 0; dd_ < 4; dd_++) {                                    \
      u16x4 val_ = {vr[0][dd_], vr[1][dd_], vr[2][dd_], vr[3][dd_]};       \
      *(u16x4*)(lds + 16384 + (buf) * 8192 + swz(dv + dd_, sv * 2)) = val_;\
    } } while (0)

  const int q0 = qt << 6;
  const int qg = q0 + w * 16 + r;

  i32x4 qf[2];
  qf[0] = *(const i32x4*)(Qb + (size_t)(q0 + w * 16 + r) * 64 + gq * 8);
  qf[1] = *(const i32x4*)(Qb + (size_t)(q0 + w * 16 + r) * 64 + 32 + gq * 8);

  STAGEK(0, 0);
  LOADV(0);
  WRITEV(0);
  __syncthreads();

  f32x4 accO[4] = {};
  float m_run = -1e30f, l_run = 0.0f;

  for (int t = 0; t <= qt; t++) {
    const int cb = t & 1, nb = cb ^ 1;
    const bool diag = (t == qt);
    const int s0 = t << 6;
    if (!diag) {            // issue next-tile loads BEFORE compute
      STAGEK(s0 + 64, nb);
      LOADV(s0 + 64);
    }

    // S^T = K * Q^T : lane (gq,r) gets S[s=sb*16+gq*4+e][q=r]
    f32x4 st[4] = {};
    const int sbmax = diag ? (w + 1) : 4;
    #pragma unroll
    for (int kd = 0; kd < 2; kd++)
      #pragma unroll
      for (int sb = 0; sb < 4; sb++)
        if (sb < sbmax) {
          i32x4 kf = *(const i32x4*)(lds + cb * 8192 + swz(sb * 16 + r, kd * 64 + gq * 16));
          mfma16(st[sb], kf, qf[kd]);
        }

    float tmax = -1e30f;
    if (diag) {
      #pragma unroll
      for (int sb = 0; sb < 4; sb++)
        #pragma unroll
        for (int e = 0; e < 4; e++) {
          int sg = s0 + sb * 16 + gq * 4 + e;
          float v = st[sb][e] * SC2;
          v = (sg <= qg) ? v : -1e30f;
          st[sb][e] = v;
          tmax = fmaxf(tmax, v);
        }
    } else {
      #pragma unroll
      for (int sb = 0; sb < 4; sb++)
        #pragma unroll
        for (int e = 0; e < 4; e++) {
          float v = st[sb][e] * SC2;
          st[sb][e] = v;
          tmax = fmaxf(tmax, v);
        }
    }
    tmax = fmaxf(tmax, __shfl_xor(tmax, 16));
    tmax = fmaxf(tmax, __shfl_xor(tmax, 32));

    // online softmax (log2 domain); m_run/l_run lane-local per q=r
    if (!__all(tmax <= m_run)) {
      const float mnew = fmaxf(m_run, tmax);
      const float alpha = exp2_hw(m_run - mnew);
      l_run *= alpha;
      #pragma unroll
      for (int db = 0; db < 4; db++)
        #pragma unroll
        for (int e = 0; e < 4; e++) accO[db][e] *= alpha;
      m_run = mnew;
    }
    float rsum = 0.0f;
    #pragma unroll
    for (int sb = 0; sb < 4; sb++)
      #pragma unroll
      for (int e = 0; e < 4; e++) {
        float pv = exp2_hw(st[sb][e] - m_run);
        st[sb][e] = pv;
        rsum += pv;
      }
    rsum += __shfl_xor(rsum, 16);
    rsum += __shfl_xor(rsum, 32);
    l_run += rsum;

    // O^T += V^T * P^T  (P packed in-register; k-map matches V^T read)
    const int kmax = diag ? ((w >> 1) + 1) : 2;
    #pragma unroll
    for (int ks = 0; ks < 2; ks++)
      if (ks < kmax) {
        u32 w0, w1, w2, w3;
        asm("v_cvt_pk_bf16_f32 %0, %1, %2" : "=v"(w0) : "v"(st[2*ks][0]),   "v"(st[2*ks][1]));
        asm("v_cvt_pk_bf16_f32 %0, %1, %2" : "=v"(w1) : "v"(st[2*ks][2]),   "v"(st[2*ks][3]));
        asm("v_cvt_pk_bf16_f32 %0, %1, %2" : "=v"(w2) : "v"(st[2*ks+1][0]), "v"(st[2*ks+1][1]));
        asm("v_cvt_pk_bf16_f32 %0, %1, %2" : "=v"(w3) : "v"(st[2*ks+1][2]), "v"(st[2*ks+1][3]));
        i32x4 pf = {(int)w0, (int)w1, (int)w2, (int)w3};
        #pragma unroll
        for (int db = 0; db < 4; db++) {
          uint2 a0 = *(const uint2*)(lds + 16384 + cb * 8192 + swz(db * 16 + r, ks * 64 + gq * 8));
          uint2 a1 = *(const uint2*)(lds + 16384 + cb * 8192 + swz(db * 16 + r, ks * 64 + gq * 8 + 32));
          i32x4 vfr = {(int)a0.x, (int)a0.y, (int)a1.x, (int)a1.y};
          mfma16(accO[db], vfr, pf);
        }
      }

    if (!diag) WRITEV(nb);
    __syncthreads();
  }

  // epilogue: accO[db][e] = O[q=q0+w*16+r][d=db*16+gq*4+e], scale 1/l (lane-local)
  const float li = 1.0f / l_run;
  const int qrow = q0 + w * 16 + r;
  #pragma unroll
  for (int db = 0; db < 4; db++) {
    u16x4 ov;
    #pragma unroll
    for (int e = 0; e < 4; e++) ov[e] = f2b(accO[db][e] * li);
    *(u16x4*)(O + (size_t)(bb * 2048 + qrow) * 512 + hh * 64 + db * 16 + gq * 4) = ov;
  }
#undef STAGEK
#undef LOADV
#undef WRITEV
}

// ---------------- launcher ----------------
extern "C" void kernel_launch(void* const* d_in, const int* in_sizes, int n_in,
                              void* d_out, int out_size, void* d_ws, size_t ws_size,
                              hipStream_t stream)
{
  const float* x    = (const float*)d_in[0];
  const float* ln1g = (const float*)d_in[1];
  const float* ln1b = (const float*)d_in[2];
  const float* Wq   = (const float*)d_in[3];
  const float* bq   = (const float*)d_in[4];
  const float* Wk   = (const float*)d_in[5];
  const float* bk   = (const float*)d_in[6];
  const float* Wv   = (const float*)d_in[7];
  const float* bv   = (const float*)d_in[8];
  const float* Wp   = (const float*)d_in[9];
  const float* bp   = (const float*)d_in[10];
  const float* ln2g = (const float*)d_in[11];
  const float* ln2b = (const float*)d_in[12];
  const float* W1   = (const float*)d_in[13];
  const float* b1   = (const float*)d_in[14];
  const float* W2   = (const float*)d_in[15];
  const float* b2   = (const float*)d_in[16];

  char* ws = (char*)d_ws;
  const size_t MB = 1ull << 20;
  u16* x1b   = (u16*)(ws);                // 8 MB bf16 [8192,512] (x + attn)
  u16* hbuf  = (u16*)(ws + 16 * MB);      // 8 MB
  u16* Qb    = (u16*)(ws + 24 * MB);      // 8 MB  [B,H,T,64]
  u16* Kb    = (u16*)(ws + 32 * MB);      // 8 MB
  u16* Vb    = (u16*)(ws + 40 * MB);      // 8 MB
  u16* attn  = (u16*)(ws + 48 * MB);      // 8 MB  [8192,512]
  u16* fbuf  = (u16*)(ws + 24 * MB);      // 32 MB [8192,2048] (reuses dead QKV+attn)
  u16* Wqkv  = (u16*)(ws + 56 * MB);      // 1.5 MB [1536,512]
  u16* Wpt   = (u16*)(ws + 58 * MB);      // 0.5 MB [512,512]
  u16* W1t   = (u16*)(ws + 59 * MB);      // 2 MB  [2048,512]
  u16* W2t   = (u16*)(ws + 61 * MB);      // 2 MB  [512,2048]
  float* outf = (float*)d_out;

  prep_ln<<<2816, 256, 0, stream>>>(x, ln1g, ln1b, hbuf,
                                    Wq, Wk, Wv, Wqkv,
                                    Wp, Wpt, W1, W1t, W2, W2t);
  gemm_bt<512, 128, 0><<<768, 256, 0, stream>>>(hbuf, Wqkv, bq, bk, bv,
                                                nullptr, Qb, Kb, Vb);
  attn_kernel<<<1024, 256, 0, stream>>>(Qb, Kb, Vb, attn);
  gemm_bt<512, 64, 3><<<512, 256, 0, stream>>>(attn, Wpt, bp, nullptr, nullptr,
                                               x, x1b, nullptr, nullptr);
  ln_kernel_b<<<2048, 256, 0, stream>>>(x1b, ln2g, ln2b, hbuf);
  gemm_bt<512, 128, 2><<<1024, 256, 0, stream>>>(hbuf, W1t, b1, nullptr, nullptr,
                                                 nullptr, fbuf, nullptr, nullptr);
  gemm_bt<2048, 64, 4><<<512, 256, 0, stream>>>(fbuf, W2t, b2, nullptr, nullptr,
                                                (const float*)x1b, outf, nullptr, nullptr);
}

// Round 25
// 156.984 us; speedup vs baseline: 1.1256x; 1.0163x over previous
//
#include <hip/hip_runtime.h>

typedef unsigned short u16;
typedef unsigned int   u32;
typedef __attribute__((ext_vector_type(4))) int   i32x4;
typedef __attribute__((ext_vector_type(4))) float f32x4;
typedef __attribute__((ext_vector_type(4))) unsigned short u16x4;
typedef __attribute__((ext_vector_type(8))) unsigned short u16x8;

#define DEVI static __device__ __forceinline__

DEVI u16 f2b(float f) {
  u32 u = __builtin_bit_cast(u32, f);
  return (u16)((u + 0x7FFFu + ((u >> 16) & 1u)) >> 16);   // RNE
}

DEVI float b2f(u16 v) {
  u32 u = (u32)v << 16;
  return __builtin_bit_cast(float, u);
}

DEVI float exp2_hw(float x) {          // D = 2^S0 (v_exp_f32)
  float r;
  asm("v_exp_f32 %0, %1" : "=v"(r) : "v"(x));
  return r;
}

DEVI void mfma16(f32x4& d, i32x4 a, i32x4 b) {
  asm("v_mfma_f32_16x16x32_bf16 %0, %1, %2, %0" : "+v"(d) : "v"(a), "v"(b));
}

DEVI void gload16(const void* g, void* l) {
  __builtin_amdgcn_global_load_lds(
      (const __attribute__((address_space(1))) void*)g,
      (__attribute__((address_space(3))) void*)l, 16, 0, 0);
}

// XOR swizzle for 128B-row LDS tiles (8 16B slots/row): slot ^= row&7
DEVI int swz(int row, int b) {
  return (row << 7) + (((b >> 4) ^ (row & 7)) << 4) + (b & 15);
}

// ---------------- merged prep + LN1 bodies ----------------
DEVI void trans_body(const float* __restrict__ src, u16* __restrict__ dst,
                     int R, int C, int rb, int cb, int t, u16 (*tile)[72])
{
  const int tr = t >> 2, tc = (t & 3) * 16;
  const float* sp = src + (size_t)(rb + tr) * C + cb + tc;
  #pragma unroll
  for (int q = 0; q < 4; q++) {
    float4 v = *(const float4*)(sp + q * 4);
    tile[tr][tc + q*4 + 0] = f2b(v.x);
    tile[tr][tc + q*4 + 1] = f2b(v.y);
    tile[tr][tc + q*4 + 2] = f2b(v.z);
    tile[tr][tc + q*4 + 3] = f2b(v.w);
  }
  __syncthreads();
  const int dc = t >> 2, dr = (t & 3) * 16;
  u16x8 o0, o1;
  #pragma unroll
  for (int j = 0; j < 8; j++) { o0[j] = tile[dr + j][dc]; o1[j] = tile[dr + 8 + j][dc]; }
  u16* dp = dst + (size_t)(cb + dc) * R + rb + dr;
  *(u16x8*)(dp) = o0;
  *(u16x8*)(dp + 8) = o1;
}

DEVI void ln_body(const float* __restrict__ x, const float* __restrict__ gamma,
                  const float* __restrict__ beta, u16* __restrict__ out,
                  int blk, int tid)
{
  const int lane = tid & 63;
  const int row = blk * 4 + (tid >> 6);
  const float4* xr = (const float4*)(x + (size_t)row * 512) + lane * 2;
  float4 a0 = xr[0], a1 = xr[1];
  float s  = a0.x + a0.y + a0.z + a0.w + a1.x + a1.y + a1.z + a1.w;
  float sq = a0.x*a0.x + a0.y*a0.y + a0.z*a0.z + a0.w*a0.w
           + a1.x*a1.x + a1.y*a1.y + a1.z*a1.z + a1.w*a1.w;
  #pragma unroll
  for (int o = 32; o > 0; o >>= 1) { s += __shfl_xor(s, o); sq += __shfl_xor(sq, o); }
  const float mu = s * (1.0f / 512.0f);
  const float rstd = rsqrtf(sq * (1.0f / 512.0f) - mu * mu + 1e-5f);
  const float4* g4 = (const float4*)gamma + lane * 2;
  const float4* b4 = (const float4*)beta  + lane * 2;
  float4 g0 = g4[0], g1 = g4[1], b0 = b4[0], b1 = b4[1];
  float xv[8] = {a0.x,a0.y,a0.z,a0.w,a1.x,a1.y,a1.z,a1.w};
  float gv[8] = {g0.x,g0.y,g0.z,g0.w,g1.x,g1.y,g1.z,g1.w};
  float bv[8] = {b0.x,b0.y,b0.z,b0.w,b1.x,b1.y,b1.z,b1.w};
  u16x8 ov;
  #pragma unroll
  for (int j = 0; j < 8; j++) ov[j] = f2b((xv[j] - mu) * rstd * gv[j] + bv[j]);
  *(u16x8*)(out + (size_t)row * 512 + lane * 8) = ov;
}

// grid 2816 = 2048 LN1 | 192 QKV-pack | 64 Wp | 256 W1 | 256 W2
__global__ __launch_bounds__(256) void prep_ln(
    const float* __restrict__ x, const float* __restrict__ ln1g,
    const float* __restrict__ ln1b, u16* __restrict__ hbuf,
    const float* __restrict__ Wq, const float* __restrict__ Wk,
    const float* __restrict__ Wv, u16* __restrict__ Wqkv,
    const float* __restrict__ Wp, u16* __restrict__ Wpt,
    const float* __restrict__ W1, u16* __restrict__ W1t,
    const float* __restrict__ W2, u16* __restrict__ W2t)
{
  __shared__ u16 tile[64][72];
  const int t = threadIdx.x;
  int b = blockIdx.x;
  if (b < 2048) { ln_body(x, ln1g, ln1b, hbuf, b, t); return; }
  b -= 2048;
  if (b < 192) {   // QKV pack: W_widx[h] (512x64) ^T -> Wqkv rows widx*512+h*64
    const int widx = b >> 6, h = (b >> 3) & 7, rb = (b & 7) * 64;
    const float* W = (widx == 0) ? Wq : (widx == 1) ? Wk : Wv;
    trans_body(W + (size_t)h * 512 * 64, Wqkv + (size_t)(widx * 512 + h * 64) * 512,
               512, 64, rb, 0, t, tile);
    return;
  }
  b -= 192;
  if (b < 64)  { trans_body(Wp, Wpt, 512, 512,  (b & 7) * 64, (b >> 3) * 64, t, tile); return; }
  b -= 64;
  if (b < 256) { trans_body(W1, W1t, 512, 2048, (b & 7) * 64, (b >> 3) * 64, t, tile); return; }
  b -= 256;
  trans_body(W2, W2t, 2048, 512, (b & 31) * 64, (b >> 5) * 64, t, tile);
}

// ---------------- LayerNorm over bf16 input (LN2 on x1b) ----------------
__global__ __launch_bounds__(256) void ln_kernel_b(
    const u16* __restrict__ x, const float* __restrict__ gamma,
    const float* __restrict__ beta, u16* __restrict__ out)
{
  const int tid = threadIdx.x;
  const int lane = tid & 63;
  const int row = blockIdx.x * 4 + (tid >> 6);
  u16x8 xr = *(const u16x8*)(x + (size_t)row * 512 + lane * 8);
  float xv[8];
  #pragma unroll
  for (int j = 0; j < 8; j++) xv[j] = b2f(xr[j]);
  float s = 0.0f, sq = 0.0f;
  #pragma unroll
  for (int j = 0; j < 8; j++) { s += xv[j]; sq += xv[j] * xv[j]; }
  #pragma unroll
  for (int o = 32; o > 0; o >>= 1) { s += __shfl_xor(s, o); sq += __shfl_xor(sq, o); }
  const float mu = s * (1.0f / 512.0f);
  const float rstd = rsqrtf(sq * (1.0f / 512.0f) - mu * mu + 1e-5f);
  const float4* g4 = (const float4*)gamma + lane * 2;
  const float4* b4 = (const float4*)beta  + lane * 2;
  float4 g0 = g4[0], g1 = g4[1], b0 = b4[0], b1 = b4[1];
  float gv[8] = {g0.x,g0.y,g0.z,g0.w,g1.x,g1.y,g1.z,g1.w};
  float bv[8] = {b0.x,b0.y,b0.z,b0.w,b1.x,b1.y,b1.z,b1.w};
  u16x8 ov;
  #pragma unroll
  for (int j = 0; j < 8; j++) ov[j] = f2b((xv[j] - mu) * rstd * gv[j] + bv[j]);
  *(u16x8*)(out + (size_t)row * 512 + lane * 8) = ov;
}

// ---------------- GEMM: MTx128 tile, pipelined staging ----------------
// (round-14 verified orientation; do NOT swap mfma operands — R15 refcheck fail)
// MT=128: 2-deep pipeline, 32KB LDS -> 5 blocks/CU (FFN1's 1024 blocks fully
// co-resident at 4/CU, no tail). MT=64: 3-deep, 36KB (proven).
// EPI 0: QKV scatter | EPI 2: +bias,relu->bf16 | EPI 3: +bias+fp32resid->bf16
// EPI 4: +bias+bf16resid->fp32
template<int KD, int MT, int EPI>
__global__ __launch_bounds__(256) void gemm_bt(
    const u16* __restrict__ A, const u16* __restrict__ Bt,
    const float* __restrict__ bias0, const float* __restrict__ bias1,
    const float* __restrict__ bias2, const float* __restrict__ resid,
    void* __restrict__ out0, void* __restrict__ out1, void* __restrict__ out2)
{
  constexpr int DEPTH = (MT == 128) ? 2 : 3;
  __shared__ __align__(16) u16 sA[DEPTH][MT * 32];
  __shared__ __align__(16) u16 sB[DEPTH][128 * 32];
  constexpr int NSTEP = KD / 32;
  constexpr int MTILES = 8192 / MT;
  constexpr int WC = (MT == 128) ? 2 : 4;
  constexpr int MI = 4;
  constexpr int NJ = 8 / WC;
  constexpr int LA = MT / 64;
  const int tid = threadIdx.x, lane = tid & 63, w = tid >> 6;
  const int m0 = (blockIdx.x % MTILES) * MT, n0 = (blockIdx.x / MTILES) * 128;
  const int wr = w / WC, wc = w % WC, r = lane & 15, gq = lane >> 4;

  f32x4 acc[MI][NJ] = {};

  const char* Ab = (const char*)A;
  const char* Bb = (const char*)Bt;

#define STAGE(step, buf) do {                                                  \
    const int kbyte_ = (step) * 64;                                            \
    _Pragma("unroll")                                                          \
    for (int la_ = 0; la_ < LA; la_++) {                                       \
      int o_ = la_ * 4096 + tid * 16;                                          \
      gload16(Ab + (size_t)(m0 + (o_ >> 6)) * (KD * 2) + kbyte_ + (o_ & 63),   \
              (char*)sA + (buf) * (MT * 64) + o_);                             \
    }                                                                          \
    _Pragma("unroll")                                                          \
    for (int lb_ = 0; lb_ < 2; lb_++) {                                        \
      int o_ = lb_ * 4096 + tid * 16;                                          \
      gload16(Bb + (size_t)(n0 + (o_ >> 6)) * (KD * 2) + kbyte_ + (o_ & 63),   \
              (char*)sB + (buf) * 8192 + o_);                                  \
    }                                                                          \
  } while (0)

  STAGE(0, 0);
  if constexpr (DEPTH == 3) STAGE(1, 1);

  for (int t = 0; t < NSTEP; t++) {
    __builtin_amdgcn_sched_barrier(0);
    __builtin_amdgcn_s_barrier();
    if constexpr (DEPTH == 3) {
      if (t + 2 < NSTEP) {
        STAGE(t + 2, (t + 2) % 3);
        asm volatile("s_waitcnt vmcnt(6)" ::: "memory");
      } else if (t + 1 < NSTEP) {
        asm volatile("s_waitcnt vmcnt(3)" ::: "memory");
      } else {
        asm volatile("s_waitcnt vmcnt(0)" ::: "memory");
      }
    } else {
      if (t + 1 < NSTEP) {
        STAGE(t + 1, (t + 1) & 1);
        asm volatile("s_waitcnt vmcnt(4)" ::: "memory");
      } else {
        asm volatile("s_waitcnt vmcnt(0)" ::: "memory");
      }
    }
    __builtin_amdgcn_sched_barrier(0);
    __builtin_amdgcn_s_barrier();
    const u16* sAc = sA[t % DEPTH];
    const u16* sBc = sB[t % DEPTH];
    i32x4 af[MI], bfr[NJ];
    #pragma unroll
    for (int i = 0; i < MI; i++)
      af[i] = *(const i32x4*)(sAc + (wr * (MI * 16) + i * 16 + r) * 32 + gq * 8);
    #pragma unroll
    for (int j = 0; j < NJ; j++)
      bfr[j] = *(const i32x4*)(sBc + (wc * (NJ * 16) + j * 16 + r) * 32 + gq * 8);
    #pragma unroll
    for (int i = 0; i < MI; i++)
      #pragma unroll
      for (int j = 0; j < NJ; j++)
        mfma16(acc[i][j], af[i], bfr[j]);
  }
#undef STAGE

  #pragma unroll
  for (int i = 0; i < MI; i++) {
    #pragma unroll
    for (int j = 0; j < NJ; j++) {
      const int mb = m0 + wr * (MI * 16) + i * 16 + gq * 4;
      const int nc = n0 + wc * (NJ * 16) + j * 16 + r;
      #pragma unroll
      for (int e = 0; e < 4; e++) {
        const int m = mb + e;
        float v = acc[i][j][e];
        if (EPI == 0) {
          float bias; u16* dst;
          if (nc < 512)       { bias = bias0[nc];        dst = (u16*)out0; }
          else if (nc < 1024) { bias = bias1[nc - 512];  dst = (u16*)out1; }
          else                { bias = bias2[nc - 1024]; dst = (u16*)out2; }
          v += bias;
          const int nn = nc & 511, h = nn >> 6, d = nn & 63;
          const int bb = m >> 11, tt = m & 2047;
          dst[(size_t)((bb * 8 + h) * 2048 + tt) * 64 + d] = f2b(v);
        } else if (EPI == 2) {
          v += bias0[nc];
          v = fmaxf(v, 0.0f);
          ((u16*)out0)[(size_t)m * 2048 + nc] = f2b(v);
        } else if (EPI == 3) {
          v += bias0[nc] + resid[(size_t)m * 512 + nc];
          ((u16*)out0)[(size_t)m * 512 + nc] = f2b(v);
        } else {   // EPI == 4
          const u16* rb_ = (const u16*)resid;
          v += bias0[nc] + b2f(rb_[(size_t)m * 512 + nc]);
          ((float*)out0)[(size_t)m * 512 + nc] = v;
        }
      }
    }
  }
}

// ---------------- causal flash attention v6: in-register P, O^T accumulate ---------------
// grid 1024 = 32 qslots x 32 bh (bh fastest); qt = {s,15-s,16+s,31-s} balance map.
__global__ __launch_bounds__(256) void attn_kernel(
    const u16* __restrict__ Q, const u16* __restrict__ K,
    const u16* __restrict__ V, u16* __restrict__ O)
{
  __shared__ __align__(16) char lds[32768];  // K dbuf 0..16K | Vt dbuf 16K..32K
  const int tid = threadIdx.x, lane = tid & 63, w = tid >> 6;
  const int bh = blockIdx.x & 31, i = blockIdx.x >> 5;
  const int s = i & 7, g = i >> 3;
  const int qt = (g == 0) ? s : (g == 1) ? (15 - s) : (g == 2) ? (16 + s) : (31 - s);
  const int r = lane & 15, gq = lane >> 4;
  const u16* Qb = Q + (size_t)bh * (2048 * 64);
  const u16* Kb = K + (size_t)bh * (2048 * 64);
  const u16* Vb = V + (size_t)bh * (2048 * 64);
  const int bb = bh >> 3, hh = bh & 7;

  const int sv = (tid & 15) * 4;   // V-stage: local s base
  const int dv = (tid >> 4) * 4;   // V-stage: d base
  u16x4 vr[4];
  const float SC2 = 0.125f * 1.44269504f;   // log2 domain

#define STAGEK(s0g, buf) do {                                              \
    _Pragma("unroll")                                                      \
    for (int i_ = 0; i_ < 2; i_++) {                                       \
      int o_ = w * 2048 + i_ * 1024 + lane * 16;                           \
      int so_ = o_ ^ (((o_ >> 7) & 7) << 4);                               \
      gload16((const char*)(Kb + (size_t)(s0g) * 64) + so_,                \
              lds + (buf) * 8192 + w * 2048 + i_ * 1024);                  \
    } } while (0)

#define LOADV(s0g) do {                                                    \
    _Pragma("unroll")                                                      \
    for (int j_ = 0; j_ < 4; j_++)                                         \
      vr[j_] = *(const u16x4*)(Vb + (size_t)((s0g) + sv + j_) * 64 + dv);  \
    } while (0)

#define WRITEV(buf) do {                                                   \
    _Pragma("unroll")                                                      \
    for (int dd_ = 0; dd_ < 4; dd_++) {                                    \
      u16x4 val_ = {vr[0][dd_], vr[1][dd_], vr[2][dd_], vr[3][dd_]};       \
      *(u16x4*)(lds + 16384 + (buf) * 8192 + swz(dv + dd_, sv * 2)) = val_;\
    } } while (0)

  const int q0 = qt << 6;
  const int qg = q0 + w * 16 + r;

  i32x4 qf[2];
  qf[0] = *(const i32x4*)(Qb + (size_t)(q0 + w * 16 + r) * 64 + gq * 8);
  qf[1] = *(const i32x4*)(Qb + (size_t)(q0 + w * 16 + r) * 64 + 32 + gq * 8);

  STAGEK(0, 0);
  LOADV(0);
  WRITEV(0);
  __syncthreads();

  f32x4 accO[4] = {};
  float m_run = -1e30f, l_run = 0.0f;

  for (int t = 0; t <= qt; t++) {
    const int cb = t & 1, nb = cb ^ 1;
    const bool diag = (t == qt);
    const int s0 = t << 6;
    if (!diag) {            // issue next-tile loads BEFORE compute
      STAGEK(s0 + 64, nb);
      LOADV(s0 + 64);
    }

    // S^T = K * Q^T : lane (gq,r) gets S[s=sb*16+gq*4+e][q=r]
    f32x4 st[4] = {};
    const int sbmax = diag ? (w + 1) : 4;
    #pragma unroll
    for (int kd = 0; kd < 2; kd++)
      #pragma unroll
      for (int sb = 0; sb < 4; sb++)
        if (sb < sbmax) {
          i32x4 kf = *(const i32x4*)(lds + cb * 8192 + swz(sb * 16 + r, kd * 64 + gq * 16));
          mfma16(st[sb], kf, qf[kd]);
        }

    float tmax = -1e30f;
    if (diag) {
      #pragma unroll
      for (int sb = 0; sb < 4; sb++)
        #pragma unroll
        for (int e = 0; e < 4; e++) {
          int sg = s0 + sb * 16 + gq * 4 + e;
          float v = st[sb][e] * SC2;
          v = (sg <= qg) ? v : -1e30f;
          st[sb][e] = v;
          tmax = fmaxf(tmax, v);
        }
    } else {
      #pragma unroll
      for (int sb = 0; sb < 4; sb++)
        #pragma unroll
        for (int e = 0; e < 4; e++) {
          float v = st[sb][e] * SC2;
          st[sb][e] = v;
          tmax = fmaxf(tmax, v);
        }
    }
    tmax = fmaxf(tmax, __shfl_xor(tmax, 16));
    tmax = fmaxf(tmax, __shfl_xor(tmax, 32));

    // online softmax (log2 domain); m_run/l_run lane-local per q=r
    if (!__all(tmax <= m_run)) {
      const float mnew = fmaxf(m_run, tmax);
      const float alpha = exp2_hw(m_run - mnew);
      l_run *= alpha;
      #pragma unroll
      for (int db = 0; db < 4; db++)
        #pragma unroll
        for (int e = 0; e < 4; e++) accO[db][e] *= alpha;
      m_run = mnew;
    }
    float rsum = 0.0f;
    #pragma unroll
    for (int sb = 0; sb < 4; sb++)
      #pragma unroll
      for (int e = 0; e < 4; e++) {
        float pv = exp2_hw(st[sb][e] - m_run);
        st[sb][e] = pv;
        rsum += pv;
      }
    rsum += __shfl_xor(rsum, 16);
    rsum += __shfl_xor(rsum, 32);
    l_run += rsum;

    // O^T += V^T * P^T  (P packed in-register; k-map matches V^T read)
    const int kmax = diag ? ((w >> 1) + 1) : 2;
    #pragma unroll
    for (int ks = 0; ks < 2; ks++)
      if (ks < kmax) {
        u32 w0, w1, w2, w3;
        asm("v_cvt_pk_bf16_f32 %0, %1, %2" : "=v"(w0) : "v"(st[2*ks][0]),   "v"(st[2*ks][1]));
        asm("v_cvt_pk_bf16_f32 %0, %1, %2" : "=v"(w1) : "v"(st[2*ks][2]),   "v"(st[2*ks][3]));
        asm("v_cvt_pk_bf16_f32 %0, %1, %2" : "=v"(w2) : "v"(st[2*ks+1][0]), "v"(st[2*ks+1][1]));
        asm("v_cvt_pk_bf16_f32 %0, %1, %2" : "=v"(w3) : "v"(st[2*ks+1][2]), "v"(st[2*ks+1][3]));
        i32x4 pf = {(int)w0, (int)w1, (int)w2, (int)w3};
        #pragma unroll
        for (int db = 0; db < 4; db++) {
          uint2 a0 = *(const uint2*)(lds + 16384 + cb * 8192 + swz(db * 16 + r, ks * 64 + gq * 8));
          uint2 a1 = *(const uint2*)(lds + 16384 + cb * 8192 + swz(db * 16 + r, ks * 64 + gq * 8 + 32));
          i32x4 vfr = {(int)a0.x, (int)a0.y, (int)a1.x, (int)a1.y};
          mfma16(accO[db], vfr, pf);
        }
      }

    if (!diag) WRITEV(nb);
    __syncthreads();
  }

  // epilogue: accO[db][e] = O[q=q0+w*16+r][d=db*16+gq*4+e], scale 1/l (lane-local)
  const float li = 1.0f / l_run;
  const int qrow = q0 + w * 16 + r;
  #pragma unroll
  for (int db = 0; db < 4; db++) {
    u16x4 ov;
    #pragma unroll
    for (int e = 0; e < 4; e++) ov[e] = f2b(accO[db][e] * li);
    *(u16x4*)(O + (size_t)(bb * 2048 + qrow) * 512 + hh * 64 + db * 16 + gq * 4) = ov;
  }
#undef STAGEK
#undef LOADV
#undef WRITEV
}

// ---------------- launcher ----------------
extern "C" void kernel_launch(void* const* d_in, const int* in_sizes, int n_in,
                              void* d_out, int out_size, void* d_ws, size_t ws_size,
                              hipStream_t stream)
{
  const float* x    = (const float*)d_in[0];
  const float* ln1g = (const float*)d_in[1];
  const float* ln1b = (const float*)d_in[2];
  const float* Wq   = (const float*)d_in[3];
  const float* bq   = (const float*)d_in[4];
  const float* Wk   = (const float*)d_in[5];
  const float* bk   = (const float*)d_in[6];
  const float* Wv   = (const float*)d_in[7];
  const float* bv   = (const float*)d_in[8];
  const float* Wp   = (const float*)d_in[9];
  const float* bp   = (const float*)d_in[10];
  const float* ln2g = (const float*)d_in[11];
  const float* ln2b = (const float*)d_in[12];
  const float* W1   = (const float*)d_in[13];
  const float* b1   = (const float*)d_in[14];
  const float* W2   = (const float*)d_in[15];
  const float* b2   = (const float*)d_in[16];

  char* ws = (char*)d_ws;
  const size_t MB = 1ull << 20;
  u16* x1b   = (u16*)(ws);                // 8 MB bf16 [8192,512] (x + attn)
  u16* hbuf  = (u16*)(ws + 16 * MB);      // 8 MB
  u16* Qb    = (u16*)(ws + 24 * MB);      // 8 MB  [B,H,T,64]
  u16* Kb    = (u16*)(ws + 32 * MB);      // 8 MB
  u16* Vb    = (u16*)(ws + 40 * MB);      // 8 MB
  u16* attn  = (u16*)(ws + 48 * MB);      // 8 MB  [8192,512]
  u16* fbuf  = (u16*)(ws + 24 * MB);      // 32 MB [8192,2048] (reuses dead QKV+attn)
  u16* Wqkv  = (u16*)(ws + 56 * MB);      // 1.5 MB [1536,512]
  u16* Wpt   = (u16*)(ws + 58 * MB);      // 0.5 MB [512,512]
  u16* W1t   = (u16*)(ws + 59 * MB);      // 2 MB  [2048,512]
  u16* W2t   = (u16*)(ws + 61 * MB);      // 2 MB  [512,2048]
  float* outf = (float*)d_out;

  prep_ln<<<2816, 256, 0, stream>>>(x, ln1g, ln1b, hbuf,
                                    Wq, Wk, Wv, Wqkv,
                                    Wp, Wpt, W1, W1t, W2, W2t);
  gemm_bt<512, 128, 0><<<768, 256, 0, stream>>>(hbuf, Wqkv, bq, bk, bv,
                                                nullptr, Qb, Kb, Vb);
  attn_kernel<<<1024, 256, 0, stream>>>(Qb, Kb, Vb, attn);
  gemm_bt<512, 64, 3><<<512, 256, 0, stream>>>(attn, Wpt, bp, nullptr, nullptr,
                                               x, x1b, nullptr, nullptr);
  ln_kernel_b<<<2048, 256, 0, stream>>>(x1b, ln2g, ln2b, hbuf);
  gemm_bt<512, 128, 2><<<1024, 256, 0, stream>>>(hbuf, W1t, b1, nullptr, nullptr,
                                                 nullptr, fbuf, nullptr, nullptr);
  gemm_bt<2048, 64, 4><<<512, 256, 0, stream>>>(fbuf, W2t, b2, nullptr, nullptr,
                                                (const float*)x1b, outf, nullptr, nullptr);
}